// Round 5
// baseline (4776.778 us; speedup 1.0000x reference)
//
#include <hip/hip_runtime.h>
#include <math.h>

#define N    257     // state dim
#define AP   258     // doubles per A row (cols 0..256 = S, col 257 = rhs)
#define MM   128     // rotation pairs
#define LL   512     // seq length
#define BB   4       // batch
#define NB   32      // panel width
#define PSTR 260     // P column stride (doubles), indexed by GLOBAL row 0..256
#define CHUNK 128    // trailing-column chunk (bounds U12 LDS)
#define UST  130     // U12 row stride (doubles)
#define U11S 33      // U11 row stride (32 vals + pinv at [32])

// ws byte layout:
//   A   (double) at byte 0      : 257*258*8 = 530448 B
//   w0  (float)  at byte 530448 : 257*4
//   cxy (float)  at byte 531488 : B*L*2*4 = 16384 B
// total ~548 KB (ws >= 1.26 MB proven available by rounds 1/3/4)
#define W0_BYTE  530448
#define CXY_BYTE 531488

// ---------------------------------------------------------------------------
// Kernel 1: prefix sums of x[b,:,comp] over l (theta is separable:
// theta[b,l,m] = cx[b,l]*om[m,0] + cy[b,l]*om[m,1]). 8 series, 1 wave each.
// ---------------------------------------------------------------------------
__global__ __launch_bounds__(512) void scan_kernel(const float* __restrict__ x,
                                                   float* __restrict__ ws) {
  const int tid  = threadIdx.x;
  const int wave = tid >> 6, lane = tid & 63;
  const int b    = wave >> 1, comp = wave & 1;

  const float* xp = x + ((size_t)b * LL) * 2 + comp;
  double loc[8];
  double run = 0.0;
  #pragma unroll
  for (int e = 0; e < 8; ++e) {
    run += (double)xp[(lane * 8 + e) * 2];
    loc[e] = run;
  }
  double tot = run;
  #pragma unroll
  for (int off = 1; off < 64; off <<= 1) {
    const double o = __shfl_up(tot, off);
    if (lane >= off) tot += o;
  }
  const double excl = tot - run;
  float* cp = (float*)((char*)ws + CXY_BYTE) + ((size_t)b * LL) * 2 + comp;
  #pragma unroll
  for (int e = 0; e < 8; ++e)
    cp[(lane * 8 + e) * 2] = (float)(excl + loc[e]);
}

// ---------------------------------------------------------------------------
// Kernel 2: solve S w0 = z0. Single block, 512 threads. fp64 UNPIVOTED
// panel-blocked Gauss-Jordan:
//   - panel factor: rows in REGISTERS; 64-row diagonal block factored inside
//     wave 0 via shfl broadcasts (no barriers); remaining rows do a fully
//     unrolled register triangular pass vs U11 (LDS broadcast reads).
//   - U12 = L11^-1 A12 and M01 = A01 U11^-1 per trailing chunk; Jordan GEMM
//     updates rows [0,k0) U [ct,N) in fp64 with double2 LDS reads.
//   - finish: x256 division + 8 independent per-panel 32-step back-substs.
// ---------------------------------------------------------------------------
__global__ __launch_bounds__(512) void solve_kernel(const float* __restrict__ z0,
                                                    const float* __restrict__ S,
                                                    void* __restrict__ wsv) {
  __shared__ __align__(16) double P[NB * PSTR];    // 66560 B
  __shared__ __align__(16) double U12[NB * UST];   // 33280 B
  __shared__ double U11[NB * U11S];                //  8448 B
  __shared__ double xs[N];
  __shared__ double rr[256];

  const int tid = threadIdx.x;
  double* A   = (double*)wsv;
  float*  w0f = (float*)((char*)wsv + W0_BYTE);

  // stage A = [S | z0] in fp64
  for (int idx = tid; idx < N * N; idx += 512) {
    const int i = idx / N, j = idx - i * N;
    A[i * AP + j] = (double)S[idx];
  }
  for (int i = tid; i < N; i += 512) A[i * AP + N] = (double)z0[i];
  __syncthreads();

  for (int p = 0; p < 8; ++p) {
    const int k0 = p * NB;
    const int ct = k0 + NB;
    const int nrows = N - k0;
    const bool act = tid < nrows;
    const int myrow = k0 + tid;

    // ---- panel factor, rows in registers ----
    double r[NB];
    if (act) {
      #pragma unroll
      for (int c = 0; c < NB; ++c) r[c] = A[myrow * AP + k0 + c];
    }

    if (tid < 64) {
      // wave 0 holds rows k0..k0+63 (all 32 pivot rows): factor via shfl
      #pragma unroll
      for (int j = 0; j < NB; ++j) {
        const double ujj  = __shfl(r[j], j);
        const double pinv = 1.0 / ujj;
        const double m = r[j] * pinv;
        #pragma unroll
        for (int j2 = j + 1; j2 < NB; ++j2) {
          const double u = __shfl(r[j2], j);
          if (tid > j && act) r[j2] -= m * u;
        }
        if (tid > j && act) r[j] = m;
      }
      if (tid < NB) {
        // publish U11 row tid (+pinv) to LDS and to A (for the finish)
        #pragma unroll
        for (int c = 0; c < NB; ++c) {
          U11[tid * U11S + c] = r[c];
          A[(k0 + tid) * AP + (k0 + c)] = r[c];
        }
        U11[tid * U11S + NB] = 1.0 / r[tid];   // r[tid] = diagonal u_tt
      }
    }
    __syncthreads();

    // waves 1..7: rows k0+64.., register triangular pass vs U11
    if (tid >= 64 && act) {
      #pragma unroll
      for (int j = 0; j < NB; ++j) {
        const double m = r[j] * U11[j * U11S + NB];
        r[j] = m;
        #pragma unroll
        for (int j2 = j + 1; j2 < NB; ++j2)
          r[j2] -= m * U11[j * U11S + j2];
      }
    }
    // write factored panel (multipliers / U11 mix) into P[c][globalrow]
    if (act) {
      #pragma unroll
      for (int c = 0; c < NB; ++c) P[c * PSTR + myrow] = r[c];
    }
    __syncthreads();

    // ---- trailing chunks ----
    for (int cb = ct; cb < 258; cb += CHUNK) {
      const int cc = (258 - cb < CHUNK) ? (258 - cb) : CHUNK;

      if (tid < cc) {
        // U12 column cb+tid: forward solve vs L11 (P pivot-row multipliers)
        const int c = cb + tid;
        double u[NB];
        #pragma unroll
        for (int jr = 0; jr < NB; ++jr) {
          double vv = A[(k0 + jr) * AP + c];
          for (int t = 0; t < jr; ++t) vv -= P[t * PSTR + (k0 + jr)] * u[t];
          u[jr] = vv;
          U12[jr * UST + tid] = vv;
          A[(k0 + jr) * AP + c] = vv;
        }
      } else if (cb == ct && tid >= 256 && tid < 256 + k0) {
        // M01 row r0 = tid-256: right-solve m * U11 = a01  (once per panel)
        const int r0 = tid - 256;
        double m[NB];
        #pragma unroll
        for (int j = 0; j < NB; ++j) {
          double vv = A[r0 * AP + (k0 + j)];
          for (int t = 0; t < j; ++t) vv -= m[t] * U11[t * U11S + j];
          vv *= U11[j * U11S + NB];
          m[j] = vv;
        }
        #pragma unroll
        for (int j = 0; j < NB; ++j) P[j * PSTR + r0] = m[j];
      }
      __syncthreads();

      // Jordan GEMM: rows [0,k0) U [ct,N), cols [cb, cb+cc)
      {
        const int ntc2 = (cc + 3) >> 2;
        #pragma unroll
        for (int reg2 = 0; reg2 < 2; ++reg2) {
          const int rbase = reg2 ? ct : 0;
          const int rend  = reg2 ? N  : k0;
          const int nr = rend - rbase;
          if (nr > 0) {
            const int ntr = (nr + 3) >> 2;
            for (int tI = tid; tI < ntr * ntc2; tI += 512) {
              const int trr = tI / ntc2, tcc = tI - trr * ntc2;
              const int i0 = rbase + trr * 4, c0 = tcc * 4;
              double acc[4][4];
              #pragma unroll
              for (int rr2 = 0; rr2 < 4; ++rr2)
                #pragma unroll
                for (int c = 0; c < 4; ++c)
                  acc[rr2][c] = ((i0 + rr2) < rend && (c0 + c) < cc)
                              ? A[(i0 + rr2) * AP + cb + c0 + c] : 0.0;
              #pragma unroll
              for (int t = 0; t < NB; ++t) {
                const double2 pv0 = *(const double2*)(P + t * PSTR + i0);
                const double2 pv1 = *(const double2*)(P + t * PSTR + i0 + 2);
                const double2 uv0 = *(const double2*)(U12 + t * UST + c0);
                const double2 uv1 = *(const double2*)(U12 + t * UST + c0 + 2);
                acc[0][0] -= pv0.x * uv0.x; acc[0][1] -= pv0.x * uv0.y;
                acc[0][2] -= pv0.x * uv1.x; acc[0][3] -= pv0.x * uv1.y;
                acc[1][0] -= pv0.y * uv0.x; acc[1][1] -= pv0.y * uv0.y;
                acc[1][2] -= pv0.y * uv1.x; acc[1][3] -= pv0.y * uv1.y;
                acc[2][0] -= pv1.x * uv0.x; acc[2][1] -= pv1.x * uv0.y;
                acc[2][2] -= pv1.x * uv1.x; acc[2][3] -= pv1.x * uv1.y;
                acc[3][0] -= pv1.y * uv0.x; acc[3][1] -= pv1.y * uv0.y;
                acc[3][2] -= pv1.y * uv1.x; acc[3][3] -= pv1.y * uv1.y;
              }
              #pragma unroll
              for (int rr2 = 0; rr2 < 4; ++rr2)
                #pragma unroll
                for (int c = 0; c < 4; ++c)
                  if ((i0 + rr2) < rend && (c0 + c) < cc)
                    A[(i0 + rr2) * AP + cb + c0 + c] = acc[rr2][c];
            }
          }
        }
      }
      __syncthreads();
    } // chunk
  } // panel

  // ---- finish: x256, then 8 independent per-panel back-substitutions ----
  if (tid == 0) xs[256] = A[256 * AP + 257] / A[256 * AP + 256];
  __syncthreads();
  const double x256 = xs[256];
  if (tid < 256) rr[tid] = A[tid * AP + 257] - A[tid * AP + 256] * x256;
  __syncthreads();
  const int fp_k0 = (tid >> 5) << 5;
  const int fs    = tid & 31;
  for (int j = 31; j >= 0; --j) {
    if (tid < 256 && fs == j)
      xs[fp_k0 + j] = rr[fp_k0 + j] / A[(fp_k0 + j) * AP + (fp_k0 + j)];
    __syncthreads();
    if (tid < 256 && fs < j)
      rr[fp_k0 + fs] -= A[(fp_k0 + fs) * AP + (fp_k0 + j)] * xs[fp_k0 + j];
    __syncthreads();
  }
  for (int k = tid; k < N; k += 512) w0f[k] = (float)xs[k];
  if (tid == 0) w0f[256] = (float)xs[256];
}

// ---------------------------------------------------------------------------
// Kernel 3: out[(b,l), i] = sum_d S[i,d] * W[(b,l), d]
// theta on the fly: t = cx[b,l]*om[m,0] + cy[b,l]*om[m,1]
// ---------------------------------------------------------------------------
#define NL 8
__global__ __launch_bounds__(320) void combine_kernel(const float* __restrict__ S,
                                                      const float* __restrict__ om,
                                                      const void* __restrict__ wsv,
                                                      float* __restrict__ out) {
  const int tid = threadIdx.x;
  const int b  = blockIdx.y;
  const int l0 = blockIdx.x * NL;
  const float* w0  = (const float*)((const char*)wsv + W0_BYTE);
  const float* cxy = (const float*)((const char*)wsv + CXY_BYTE);
  __shared__ float Wl[NL][N];
  __shared__ float omsh[2 * MM];
  __shared__ float cxs[NL], cys[NL];

  for (int idx = tid; idx < 2 * MM; idx += 320) omsh[idx] = om[idx];
  if (tid < NL) {
    cxs[tid] = cxy[((size_t)(b * LL) + l0 + tid) * 2];
    cys[tid] = cxy[((size_t)(b * LL) + l0 + tid) * 2 + 1];
  }
  __syncthreads();

  for (int idx = tid; idx < NL * N; idx += 320) {
    const int r = idx / N;
    const int d = idx - r * N;
    float v;
    if (d == 0) {
      v = w0[0];
    } else {
      const int m = (d - 1) >> 1;
      const int pq = 2 * m + 1;
      const float t = cxs[r] * omsh[2 * m] + cys[r] * omsh[2 * m + 1];
      float s, c;
      sincosf(t, &s, &c);
      const float a0 = w0[pq], a1 = w0[pq + 1];
      v = (d & 1) ? (c * a0 - s * a1) : (s * a0 + c * a1);
    }
    Wl[r][d] = v;
  }
  __syncthreads();

  const int i = tid;
  if (i < N) {
    const float* Si = S + (size_t)i * N;
    float acc[NL];
    #pragma unroll
    for (int r = 0; r < NL; ++r) acc[r] = 0.0f;
    #pragma unroll 4
    for (int d = 0; d < N; ++d) {
      const float sv = Si[d];
      #pragma unroll
      for (int r = 0; r < NL; ++r) acc[r] += sv * Wl[r][d];
    }
    const size_t base = (size_t)(b * LL + l0) * N + i;
    #pragma unroll
    for (int r = 0; r < NL; ++r) out[base + (size_t)r * N] = acc[r];
    if (l0 + NL == LL) {
      out[(size_t)BB * LL * N + (size_t)b * N + i] = acc[NL - 1];
    }
  }
}

extern "C" void kernel_launch(void* const* d_in, const int* in_sizes, int n_in,
                              void* d_out, int out_size, void* d_ws, size_t ws_size,
                              hipStream_t stream) {
  const float* x  = (const float*)d_in[0];   // (B, L, 2)
  const float* z0 = (const float*)d_in[1];   // (D,)
  const float* om = (const float*)d_in[2];   // (M, 2)
  const float* S  = (const float*)d_in[3];   // (D, D)
  float* out = (float*)d_out;                // outputs (B,L,D) then z_final (B,D)

  hipLaunchKernelGGL(scan_kernel,    dim3(1),           dim3(512), 0, stream, x, (float*)d_ws);
  hipLaunchKernelGGL(solve_kernel,   dim3(1),           dim3(512), 0, stream, z0, S, d_ws);
  hipLaunchKernelGGL(combine_kernel, dim3(LL / NL, BB), dim3(320), 0, stream, S, om, d_ws, out);
}

// Round 6
// 534.071 us; speedup vs baseline: 8.9441x; 8.9441x over previous
//
#include <hip/hip_runtime.h>
#include <math.h>

#define N    257     // state dim
#define AP   258     // doubles per A row (cols 0..256 = S, col 257 = rhs)
#define MM   128     // rotation pairs
#define LL   512     // seq length
#define BB   4       // batch
#define NB   32      // panel width

// ws byte layout:
#define A_BYTE    0         // double[257*258] = 530448
#define W0_BYTE   530448    // float[257]  -> ends 531476
#define CXY_BYTE  531488    // float[4096] -> ends 547872
#define PW_BYTE   547904    // double[32*257] = 65792 -> ends 613696
#define U12_BYTE  613696    // double[32*226] = 57856 -> ends 671552
// total ~672 KB (ws >= 1.31 MB proven by rounds 1-5)

// ---------------------------------------------------------------------------
// prefix sums of x[b,:,comp]: theta[b,l,m] = cx[b,l]*om0[m] + cy[b,l]*om1[m]
// ---------------------------------------------------------------------------
__global__ __launch_bounds__(512) void scan_kernel(const float* __restrict__ x,
                                                   void* __restrict__ wsv) {
  const int tid  = threadIdx.x;
  const int wave = tid >> 6, lane = tid & 63;
  const int b    = wave >> 1, comp = wave & 1;

  const float* xp = x + ((size_t)b * LL) * 2 + comp;
  double loc[8];
  double run = 0.0;
  #pragma unroll
  for (int e = 0; e < 8; ++e) {
    run += (double)xp[(lane * 8 + e) * 2];
    loc[e] = run;
  }
  double tot = run;
  #pragma unroll
  for (int off = 1; off < 64; off <<= 1) {
    const double o = __shfl_up(tot, off);
    if (lane >= off) tot += o;
  }
  const double excl = tot - run;
  float* cp = (float*)((char*)wsv + CXY_BYTE) + ((size_t)b * LL) * 2 + comp;
  #pragma unroll
  for (int e = 0; e < 8; ++e)
    cp[(lane * 8 + e) * 2] = (float)(excl + loc[e]);
}

// ---------------------------------------------------------------------------
// stage A = [S | z0] in fp64, grid-wide
// ---------------------------------------------------------------------------
__global__ __launch_bounds__(256) void stage_kernel(const float* __restrict__ S,
                                                    const float* __restrict__ z0,
                                                    void* __restrict__ wsv) {
  double* A = (double*)((char*)wsv + A_BYTE);
  const int idx = blockIdx.x * 256 + threadIdx.x;
  if (idx < N * N) {
    const int i = idx / N, j = idx - i * N;
    A[i * AP + j] = (double)S[idx];
  } else {
    const int r = idx - N * N;
    if (r < N) A[r * AP + N] = (double)z0[r];
  }
}

// ---------------------------------------------------------------------------
// panel factor (1 block, 512 thr): the ONLY sequential part.
//  - wave 0: 64 rows in registers, 32-step shfl factorization (no barriers)
//  - publishes F11 (L+U mix) + pinv to LDS; U11 -> A for the finish
//  - after 1 barrier: remaining rows do register triangular pass (->Pw),
//    M01 rows [0,k0) right-solve (->Pw), U12 cols forward-solve (->U12,A)
// ---------------------------------------------------------------------------
__global__ __launch_bounds__(512) void panel_factor_kernel(void* __restrict__ wsv,
                                                           int k0) {
  __shared__ double F11[NB][NB + 1];
  __shared__ double pinv[NB];
  double* A    = (double*)((char*)wsv + A_BYTE);
  double* Pw   = (double*)((char*)wsv + PW_BYTE);
  double* U12w = (double*)((char*)wsv + U12_BYTE);
  const int tid   = threadIdx.x;
  const int ct    = k0 + NB;
  const int nrows = N - k0;
  const int tc2   = 258 - ct;          // trailing cols incl rhs
  const bool act  = tid < nrows;
  const int myrow = k0 + tid;

  double r[NB];
  if (act) {
    #pragma unroll
    for (int c = 0; c < NB; ++c) r[c] = A[myrow * AP + k0 + c];
  }

  if (tid < 64) {
    // rows k0..k0+63 (incl all 32 pivots) factored inside one wave via shfl
    #pragma unroll
    for (int j = 0; j < NB; ++j) {
      const double ujj = __shfl(r[j], j);
      const double pj  = 1.0 / ujj;
      const double m   = r[j] * pj;
      #pragma unroll
      for (int j2 = j + 1; j2 < NB; ++j2) {
        const double u = __shfl(r[j2], j);
        if (tid > j && act) r[j2] -= m * u;
      }
      if (tid > j && act) r[j] = m;
    }
    if (tid < NB) {
      #pragma unroll
      for (int c = 0; c < NB; ++c) {
        F11[tid][c] = r[c];
        A[(k0 + tid) * AP + (k0 + c)] = r[c];   // U11 (and L mults) for finish
      }
      pinv[tid] = 1.0 / r[tid];
    } else if (act) {
      #pragma unroll
      for (int c = 0; c < NB; ++c) Pw[c * N + myrow] = r[c];
    }
  }
  __syncthreads();

  if (tid >= 64 && act) {
    // rows k0+64..N: register triangular pass vs U11
    #pragma unroll
    for (int j = 0; j < NB; ++j) {
      const double m = r[j] * pinv[j];
      r[j] = m;
      #pragma unroll
      for (int j2 = j + 1; j2 < NB; ++j2) r[j2] -= m * F11[j][j2];
    }
    #pragma unroll
    for (int c = 0; c < NB; ++c) Pw[c * N + myrow] = r[c];
  } else if (tid >= 256 && tid < 256 + k0) {
    // M01 row r0: right-solve m * U11 = a01
    const int r0 = tid - 256;
    double m[NB];
    #pragma unroll
    for (int j = 0; j < NB; ++j) {
      double vv = A[r0 * AP + (k0 + j)];
      for (int t = 0; t < j; ++t) vv -= m[t] * F11[t][j];
      vv *= pinv[j];
      m[j] = vv;
    }
    #pragma unroll
    for (int j = 0; j < NB; ++j) Pw[j * N + r0] = m[j];
  }

  // U12 forward solve: depends only on F11 (+pristine pivot-row trailing A);
  // runs sequentially within each thread after its role above — no barrier.
  if (tid < tc2) {
    const int c = ct + tid;
    double u[NB];
    #pragma unroll
    for (int jr = 0; jr < NB; ++jr) {
      double vv = A[(k0 + jr) * AP + c];
      for (int t = 0; t < jr; ++t) vv -= F11[jr][t] * u[t];
      u[jr] = vv;
      U12w[jr * 226 + tid] = vv;
      A[(k0 + jr) * AP + c] = vv;   // pivot rows' trailing (incl rhs)
    }
  }
}

// ---------------------------------------------------------------------------
// panel update (grid-parallel Jordan rank-32 GEMM):
//   rows R = [0,k0) U [ct,N)  (225 rows, R-index rb; gr = rb<k0 ? rb : rb+32)
//   cols [ct, 258): A[gr][c] -= sum_t Pw[t][gr] * U12[t][c-ct]
// block tile = 32 rows x 64 cols; thread tile = 2x4.
// ---------------------------------------------------------------------------
__global__ __launch_bounds__(256) void panel_update_kernel(void* __restrict__ wsv,
                                                           int k0, int tc2) {
  __shared__ double Pl[NB][NB + 1];
  __shared__ __align__(16) double Ul[NB][66];
  double* A = (double*)((char*)wsv + A_BYTE);
  const double* Pw   = (const double*)((const char*)wsv + PW_BYTE);
  const double* U12w = (const double*)((const char*)wsv + U12_BYTE);
  const int tid = threadIdx.x;
  const int ct  = k0 + NB;
  const int rb0 = blockIdx.x * 32;
  const int c0  = blockIdx.y * 64;

  for (int i = tid; i < 32 * 32; i += 256) {
    const int t = i >> 5, rr = i & 31;
    const int rb = rb0 + rr;
    const int gr = (rb < k0) ? rb : rb + NB;
    Pl[t][rr] = (rb < 225) ? Pw[t * N + gr] : 0.0;
  }
  for (int i = tid; i < 32 * 64; i += 256) {
    const int t = i >> 6, c = i & 63;
    Ul[t][c] = (c0 + c < tc2) ? U12w[t * 226 + c0 + c] : 0.0;
  }
  __syncthreads();

  const int tr  = tid >> 4;          // 0..15 -> rows tr*2 .. +1
  const int tcx = (tid & 15) * 4;    // cols tcx .. +3
  double acc[2][4];
  #pragma unroll
  for (int rr = 0; rr < 2; ++rr) {
    const int rb = rb0 + tr * 2 + rr;
    const int gr = (rb < k0) ? rb : rb + NB;
    #pragma unroll
    for (int c = 0; c < 4; ++c)
      acc[rr][c] = (rb < 225 && (c0 + tcx + c) < tc2)
                 ? A[gr * AP + ct + c0 + tcx + c] : 0.0;
  }
  #pragma unroll
  for (int t = 0; t < NB; ++t) {
    const double p0 = Pl[t][tr * 2], p1 = Pl[t][tr * 2 + 1];
    const double2 u0 = *(const double2*)&Ul[t][tcx];
    const double2 u1 = *(const double2*)&Ul[t][tcx + 2];
    acc[0][0] -= p0 * u0.x; acc[0][1] -= p0 * u0.y;
    acc[0][2] -= p0 * u1.x; acc[0][3] -= p0 * u1.y;
    acc[1][0] -= p1 * u0.x; acc[1][1] -= p1 * u0.y;
    acc[1][2] -= p1 * u1.x; acc[1][3] -= p1 * u1.y;
  }
  #pragma unroll
  for (int rr = 0; rr < 2; ++rr) {
    const int rb = rb0 + tr * 2 + rr;
    const int gr = (rb < k0) ? rb : rb + NB;
    #pragma unroll
    for (int c = 0; c < 4; ++c)
      if (rb < 225 && (c0 + tcx + c) < tc2)
        A[gr * AP + ct + c0 + tcx + c] = acc[rr][c];
  }
}

// ---------------------------------------------------------------------------
// finish: x256 division, then 8 independent per-panel 32-step back-substs
// ---------------------------------------------------------------------------
__global__ __launch_bounds__(256) void finish_kernel(void* __restrict__ wsv) {
  __shared__ double xs[N];
  __shared__ double rr[256];
  double* A   = (double*)((char*)wsv + A_BYTE);
  float*  w0f = (float*)((char*)wsv + W0_BYTE);
  const int tid = threadIdx.x;
  if (tid == 0) xs[256] = A[256 * AP + 257] / A[256 * AP + 256];
  __syncthreads();
  const double x256 = xs[256];
  rr[tid] = A[tid * AP + 257] - A[tid * AP + 256] * x256;
  __syncthreads();
  const int fk0 = tid & ~31;
  const int fs  = tid & 31;
  for (int j = 31; j >= 0; --j) {
    if (fs == j) xs[fk0 + j] = rr[fk0 + j] / A[(fk0 + j) * AP + (fk0 + j)];
    __syncthreads();
    if (fs < j) rr[fk0 + fs] -= A[(fk0 + fs) * AP + (fk0 + j)] * xs[fk0 + j];
    __syncthreads();
  }
  w0f[tid] = (float)xs[tid];
  if (tid == 0) w0f[256] = (float)xs[256];
}

// ---------------------------------------------------------------------------
// combine: out[(b,l), i] = sum_d S[i,d] * W[(b,l), d]
// ---------------------------------------------------------------------------
#define NL 8
__global__ __launch_bounds__(320) void combine_kernel(const float* __restrict__ S,
                                                      const float* __restrict__ om,
                                                      const void* __restrict__ wsv,
                                                      float* __restrict__ out) {
  const int tid = threadIdx.x;
  const int b  = blockIdx.y;
  const int l0 = blockIdx.x * NL;
  const float* w0  = (const float*)((const char*)wsv + W0_BYTE);
  const float* cxy = (const float*)((const char*)wsv + CXY_BYTE);
  __shared__ float Wl[NL][N];
  __shared__ float omsh[2 * MM];
  __shared__ float cxs[NL], cys[NL];

  for (int idx = tid; idx < 2 * MM; idx += 320) omsh[idx] = om[idx];
  if (tid < NL) {
    cxs[tid] = cxy[((size_t)(b * LL) + l0 + tid) * 2];
    cys[tid] = cxy[((size_t)(b * LL) + l0 + tid) * 2 + 1];
  }
  __syncthreads();

  for (int idx = tid; idx < NL * N; idx += 320) {
    const int r = idx / N;
    const int d = idx - r * N;
    float v;
    if (d == 0) {
      v = w0[0];
    } else {
      const int m = (d - 1) >> 1;
      const int pq = 2 * m + 1;
      const float t = cxs[r] * omsh[2 * m] + cys[r] * omsh[2 * m + 1];
      float s, c;
      sincosf(t, &s, &c);
      const float a0 = w0[pq], a1 = w0[pq + 1];
      v = (d & 1) ? (c * a0 - s * a1) : (s * a0 + c * a1);
    }
    Wl[r][d] = v;
  }
  __syncthreads();

  const int i = tid;
  if (i < N) {
    const float* Si = S + (size_t)i * N;
    float acc[NL];
    #pragma unroll
    for (int r = 0; r < NL; ++r) acc[r] = 0.0f;
    #pragma unroll 4
    for (int d = 0; d < N; ++d) {
      const float sv = Si[d];
      #pragma unroll
      for (int r = 0; r < NL; ++r) acc[r] += sv * Wl[r][d];
    }
    const size_t base = (size_t)(b * LL + l0) * N + i;
    #pragma unroll
    for (int r = 0; r < NL; ++r) out[base + (size_t)r * N] = acc[r];
    if (l0 + NL == LL) {
      out[(size_t)BB * LL * N + (size_t)b * N + i] = acc[NL - 1];
    }
  }
}

extern "C" void kernel_launch(void* const* d_in, const int* in_sizes, int n_in,
                              void* d_out, int out_size, void* d_ws, size_t ws_size,
                              hipStream_t stream) {
  const float* x  = (const float*)d_in[0];   // (B, L, 2)
  const float* z0 = (const float*)d_in[1];   // (D,)
  const float* om = (const float*)d_in[2];   // (M, 2)
  const float* S  = (const float*)d_in[3];   // (D, D)
  float* out = (float*)d_out;                // outputs (B,L,D) then z_final (B,D)

  hipLaunchKernelGGL(scan_kernel,  dim3(1),   dim3(512), 0, stream, x, d_ws);
  hipLaunchKernelGGL(stage_kernel, dim3(260), dim3(256), 0, stream, S, z0, d_ws);
  for (int p = 0; p < 8; ++p) {
    const int k0  = p * NB;
    const int tc2 = 258 - (k0 + NB);
    hipLaunchKernelGGL(panel_factor_kernel, dim3(1), dim3(512), 0, stream, d_ws, k0);
    hipLaunchKernelGGL(panel_update_kernel, dim3(8, (tc2 + 63) / 64), dim3(256),
                       0, stream, d_ws, k0, tc2);
  }
  hipLaunchKernelGGL(finish_kernel, dim3(1), dim3(256), 0, stream, d_ws);
  hipLaunchKernelGGL(combine_kernel, dim3(LL / NL, BB), dim3(320), 0, stream, S, om, d_ws, out);
}